// Round 1
// baseline (2731.579 us; speedup 1.0000x reference)
//
#include <hip/hip_runtime.h>
#include <hip/hip_bf16.h>
#include <stdint.h>

// Problem constants (B=64, L=512, H=32, D=128, 21 amino acids)
#define NH   32
#define NL   512
#define ND   128
#define NB   64
#define NAA  21

// ws layout:
//   Ew  : uint32[NH*NL*256]  packed bf16 pairs of exp(scores)   16 MB @ 0
//   Kt  : float [NH*32*NL*4] K transposed [h][d4][j][4]          8 MB @ 16MB
//   x2g : uint32[256*64]     packed bin-index pairs             64 KB @ 24MB
//   Zg  : float [NH*NL]      row sums of exp                    64 KB @ 24MB+64KB
#define EW_OFF  0
#define KT_OFF  (16u << 20)
#define X2_OFF  (24u << 20)
#define ZG_OFF  ((24u << 20) + 65536u)

__device__ __forceinline__ uint32_t bf16rtn(float f) {
    uint32_t u = __float_as_uint(f);
    return (u + 0x7fffu + ((u >> 16) & 1u)) >> 16;
}

// ---------------------------------------------------------------------------
// Pack bin indices: x2g[w*64+b] = (c(b,w)*64+b) | ((c(b,w+256)*64+b) << 16)
// where c(b,j) = x[b,j].  Word index into R is (c*64 + b); phase-B recovers
// c = val >> 6.
__global__ void prep_x2(const int* __restrict__ x, uint32_t* __restrict__ x2g) {
    int tid = blockIdx.x * 256 + threadIdx.x;   // 0..16383
    int w = tid >> 6, b = tid & 63;
    uint32_t c0 = (uint32_t)x[b * NL + w];
    uint32_t c1 = (uint32_t)x[b * NL + w + 256];
    x2g[tid] = ((c0 << 6) | (uint32_t)b) | ((((c1 << 6) | (uint32_t)b)) << 16);
}

// ---------------------------------------------------------------------------
// K transpose: Kt[(h*32+d4)*512 + j][0..3] = K[h][j][d4*4 .. d4*4+3]
__global__ void prep_kt(const float* __restrict__ K, float* __restrict__ Kt) {
    int tid = blockIdx.x * 256 + threadIdx.x;   // 0..524287
    int d4 = tid & 31;
    int j  = (tid >> 5) & 511;
    int h  = tid >> 14;
    float4 v = *(const float4*)(K + (((size_t)h * NL + j) * ND + d4 * 4));
    *(float4*)(Kt + (((size_t)h * 32 + d4) * NL + j) * 4) = v;
}

// ---------------------------------------------------------------------------
// scores+exp: block = (h, 8 rows i0..i0+7), 256 threads, thread owns j = t
// and j = t+256.  K via coalesced float4 from Kt; Q via block-uniform loads
// (scalarized to s_load).  Emits packed-bf16 exp(score) pairs + row sums Z.
__global__ void scores_exp(const float* __restrict__ Q, const float* __restrict__ Kt,
                           uint32_t* __restrict__ Ew, float* __restrict__ Zg) {
    int h  = blockIdx.x >> 6;
    int i0 = (blockIdx.x & 63) * 8;
    int t  = threadIdx.x;
    const float4* kt = (const float4*)Kt + (size_t)h * (32 * NL);
    const float*  qb = Q + ((size_t)h * NL + i0) * ND;

    float acc0[8], acc1[8];
#pragma unroll
    for (int ii = 0; ii < 8; ++ii) { acc0[ii] = 0.f; acc1[ii] = 0.f; }

    for (int d4 = 0; d4 < 32; ++d4) {
        float4 k1 = kt[d4 * NL + t];
        float4 k2 = kt[d4 * NL + t + 256];
#pragma unroll
        for (int ii = 0; ii < 8; ++ii) {
            float4 q = *(const float4*)(qb + ii * ND + d4 * 4);  // uniform
            acc0[ii] += q.x * k1.x + q.y * k1.y + q.z * k1.z + q.w * k1.w;
            acc1[ii] += q.x * k2.x + q.y * k2.y + q.z * k2.z + q.w * k2.w;
        }
    }

    __shared__ float zp[4][8];
    int lane = t & 63, wv = t >> 6;
#pragma unroll
    for (int ii = 0; ii < 8; ++ii) {
        float e0 = __expf(acc0[ii] * 0.0078125f);   // scores = dot/128
        float e1 = __expf(acc1[ii] * 0.0078125f);
        Ew[((size_t)h * NL + i0 + ii) * 256 + t] = bf16rtn(e0) | (bf16rtn(e1) << 16);
        float z = e0 + e1;
#pragma unroll
        for (int off = 32; off > 0; off >>= 1) z += __shfl_xor(z, off);
        if (lane == 0) zp[wv][ii] = z;
    }
    __syncthreads();
    if (t < 8) Zg[(size_t)h * NL + i0 + t] = zp[0][t] + zp[1][t] + zp[2][t] + zp[3][t];
}

// ---------------------------------------------------------------------------
// energy: block = (h, 32 rows), 512 threads = 8 waves, lane = batch b.
// Per (h,i): bin exp-scores into R[c*64+b] with ds_add_f32 (bank = b%32,
// conflict-free), then dot 21 bins against V[h, x[b,i], :], scale by 1/Z.
#define SMEM2 110592   // 64K x2 table + 8*5376 R + 1792 V + 256 eacc
__global__ void energy_k(const uint32_t* __restrict__ Ew, const uint32_t* __restrict__ x2g,
                         const float* __restrict__ Zg, const float* __restrict__ V,
                         float* __restrict__ out) {
    extern __shared__ uint8_t smem[];
    uint32_t* x2s = (uint32_t*)smem;                       // 16384 words
    float*    Rall = (float*)(smem + 65536);               // 8 * 1344 floats
    float*    Vs   = (float*)(smem + 65536 + 43008);       // 441 floats
    float*    eacc = (float*)(smem + 110336);              // 64 floats

    int h  = blockIdx.x >> 4;
    int i0 = (blockIdx.x & 15) * 32;
    int t = threadIdx.x, lane = t & 63, wv = t >> 6;

    for (int idx = t; idx < 16384; idx += 512) x2s[idx] = x2g[idx];
    for (int idx = t; idx < NAA * NAA; idx += 512) Vs[idx] = V[h * (NAA * NAA) + idx];
    if (t < 64) eacc[t] = 0.f;
    float* Rw = Rall + wv * (NAA * 64);
#pragma unroll
    for (int c = 0; c < NAA; ++c) Rw[c * 64 + lane] = 0.f;
    __syncthreads();

    float esum = 0.f;
    for (int ii = 0; ii < 4; ++ii) {
        int i = __builtin_amdgcn_readfirstlane(i0 + wv * 4 + ii);
        const uint32_t* erow = Ew + ((size_t)h * NL + i) * 256;
#pragma unroll 8
        for (int w = 0; w < 256; ++w) {
            uint32_t aw = erow[w];                 // uniform -> s_load
            uint32_t xw = x2s[w * 64 + lane];      // bank = lane%32, free
            atomicAdd(&Rw[xw & 0xffffu], __uint_as_float(aw << 16));
            atomicAdd(&Rw[xw >> 16],     __uint_as_float(aw & 0xffff0000u));
        }
        // phase B: dot V[h, x[b,i], :] with bins, scaled by 1/Z
        uint32_t xiw = x2s[(i & 255) * 64 + lane];
        uint32_t xi  = (i < 256) ? (xiw & 0xffffu) : (xiw >> 16);
        int ci = (int)(xi >> 6);
        const float* vrow = Vs + ci * NAA;
        float dot = 0.f;
#pragma unroll
        for (int c = 0; c < NAA; ++c) dot += vrow[c] * Rw[c * 64 + lane];
        esum += dot / Zg[(size_t)h * NL + i];
#pragma unroll
        for (int c = 0; c < NAA; ++c) Rw[c * 64 + lane] = 0.f;   // re-zero
    }
    atomicAdd(&eacc[lane], esum);
    __syncthreads();
    if (t < 64) atomicAdd(&out[t], -eacc[t]);
}

// ---------------------------------------------------------------------------
extern "C" void kernel_launch(void* const* d_in, const int* in_sizes, int n_in,
                              void* d_out, int out_size, void* d_ws, size_t ws_size,
                              hipStream_t stream) {
    const int*   x = (const int*)d_in[0];
    const float* Q = (const float*)d_in[1];
    const float* K = (const float*)d_in[2];
    const float* V = (const float*)d_in[3];
    float* out = (float*)d_out;
    uint8_t* ws = (uint8_t*)d_ws;

    uint32_t* Ew  = (uint32_t*)(ws + EW_OFF);
    float*    Kt  = (float*)(ws + KT_OFF);
    uint32_t* x2g = (uint32_t*)(ws + X2_OFF);
    float*    Zg  = (float*)(ws + ZG_OFF);

    hipMemsetAsync(d_out, 0, NB * sizeof(float), stream);
    prep_x2<<<64, 256, 0, stream>>>(x, x2g);
    prep_kt<<<2048, 256, 0, stream>>>(K, Kt);
    scores_exp<<<2048, 256, 0, stream>>>(Q, Kt, Ew, Zg);
    (void)hipFuncSetAttribute((const void*)energy_k,
                              hipFuncAttributeMaxDynamicSharedMemorySize, SMEM2);
    energy_k<<<512, 512, SMEM2, stream>>>(Ew, x2g, Zg, V, out);
}

// Round 2
// 173.543 us; speedup vs baseline: 15.7400x; 15.7400x over previous
//
#include <hip/hip_runtime.h>
#include <hip/hip_bf16.h>
#include <stdint.h>

// Problem constants (B=64, L=512, H=32, D=128, 21 amino acids)
#define NH   32
#define NL   512
#define ND   128
#define NB   64
#define NAA  21

// ws layout:
//   Ew  : uint32[NH*NL*256]  packed bf16 pairs of exp(scores), natural j order  16 MB @ 0
//   Kt  : float [NH*32*NL*4] K transposed [h][d4][j][4]                          8 MB @ 16MB
//   Zg  : float [NH*NL]      row sums of exp                                    64 KB @ 24MB
#define EW_OFF  0
#define KT_OFF  (16u << 20)
#define ZG_OFF  (24u << 20)

typedef short   bf16x8 __attribute__((ext_vector_type(8)));
typedef float   f32x4  __attribute__((ext_vector_type(4)));

__device__ __forceinline__ uint32_t bf16rtn(float f) {
    uint32_t u = __float_as_uint(f);
    return (u + 0x7fffu + ((u >> 16) & 1u)) >> 16;
}

// ---------------------------------------------------------------------------
// K transpose: Kt[(h*32+d4)*512 + j][0..3] = K[h][j][d4*4 .. d4*4+3]
__global__ void prep_kt(const float* __restrict__ K, float* __restrict__ Kt) {
    int tid = blockIdx.x * 256 + threadIdx.x;   // 0..524287
    int d4 = tid & 31;
    int j  = (tid >> 5) & 511;
    int h  = tid >> 14;
    float4 v = *(const float4*)(K + (((size_t)h * NL + j) * ND + d4 * 4));
    *(float4*)(Kt + (((size_t)h * 32 + d4) * NL + j) * 4) = v;
}

// ---------------------------------------------------------------------------
// scores+exp: block = (h, 8 rows), 256 threads, thread owns j = 2t and 2t+1
// so the packed-bf16 Ew row is in NATURAL j order (element k = j).
__global__ void scores_exp(const float* __restrict__ Q, const float* __restrict__ Kt,
                           uint32_t* __restrict__ Ew, float* __restrict__ Zg) {
    int h  = blockIdx.x >> 6;
    int i0 = (blockIdx.x & 63) * 8;
    int t  = threadIdx.x;
    const float4* kt = (const float4*)Kt + (size_t)h * (32 * NL);
    const float*  qb = Q + ((size_t)h * NL + i0) * ND;

    float acc0[8], acc1[8];
#pragma unroll
    for (int ii = 0; ii < 8; ++ii) { acc0[ii] = 0.f; acc1[ii] = 0.f; }

    for (int d4 = 0; d4 < 32; ++d4) {
        float4 k1 = kt[d4 * NL + 2 * t];
        float4 k2 = kt[d4 * NL + 2 * t + 1];
#pragma unroll
        for (int ii = 0; ii < 8; ++ii) {
            float4 q = *(const float4*)(qb + ii * ND + d4 * 4);  // block-uniform
            acc0[ii] += q.x * k1.x + q.y * k1.y + q.z * k1.z + q.w * k1.w;
            acc1[ii] += q.x * k2.x + q.y * k2.y + q.z * k2.z + q.w * k2.w;
        }
    }

    __shared__ float zp[4][8];
    int lane = t & 63, wv = t >> 6;
#pragma unroll
    for (int ii = 0; ii < 8; ++ii) {
        float e0 = __expf(acc0[ii] * 0.0078125f);   // scores = dot/128
        float e1 = __expf(acc1[ii] * 0.0078125f);
        Ew[((size_t)h * NL + i0 + ii) * 256 + t] = bf16rtn(e0) | (bf16rtn(e1) << 16);
        float z = e0 + e1;
#pragma unroll
        for (int off = 32; off > 0; off >>= 1) z += __shfl_xor(z, off);
        if (lane == 0) zp[wv][ii] = z;
    }
    __syncthreads();
    if (t < 8) Zg[(size_t)h * NL + i0 + t] = zp[0][t] + zp[1][t] + zp[2][t] + zp[3][t];
}

// ---------------------------------------------------------------------------
// GEMM + epilogue: block = (h, i-tile of 64, b-tile of 8).
//   R[i, bb*32+c] = sum_k E[h, i0+i, k] * [x[bt*8+bb, k] == c]   (bf16 MFMA)
//   energy contrib = sum_c R[i,bb,c] * V[h, x[b, i0+i], c] / Z[h, i0+i]
// One-hot B operand is GENERATED into LDS from x each K-chunk.
// LDS: acc region [0, 65792) reuses A/B tile space after the K-loop.
#define BM 64
#define BK 64
#define ACC_OFF 0          // 64*257*4 = 65792 B   (epilogue phase)
#define AS_OFF  0          // 64*64*2  = 8192  B   (K-loop phase)
#define BS_OFF  8192       // 256*64*2 = 32768 B   (K-loop phase)
#define XS_OFF  65792      // 1024 u32 (packed x bytes)         4096 B
#define VS_OFF  69888      // 441 f32                           1764 B
#define LDS_TOT 71680

__global__ __launch_bounds__(512, 2)
void gemm_energy(const uint32_t* __restrict__ Ew, const int* __restrict__ x,
                 const float* __restrict__ Zg, const float* __restrict__ V,
                 float* __restrict__ out) {
    extern __shared__ uint8_t smem[];
    uint32_t* xs = (uint32_t*)(smem + XS_OFF);
    float*    Vs = (float*)(smem + VS_OFF);
    uint8_t*  As = smem + AS_OFF;
    uint8_t*  Bs = smem + BS_OFF;

    int bid = blockIdx.x;
    int bt = bid & 7;            // batch tile (8 batches)
    int it = (bid >> 3) & 7;     // i tile (64 rows)
    int h  = bid >> 6;
    int t = threadIdx.x, lane = t & 63, wv = t >> 6;
    int wm = wv >> 2, wn = wv & 3;   // 2(M) x 4(N) wave grid

    // stage x bytes: xs[bb*128 + w] packs x[bt*8+bb][4w .. 4w+3]
    for (int w = t; w < 1024; w += 512) {
        int bb = w >> 7;
        int k4 = (w & 127) * 4;
        int4 xv = *(const int4*)(x + (size_t)(bt * 8 + bb) * NL + k4);
        xs[w] = (uint32_t)(xv.x & 0xff) | ((uint32_t)(xv.y & 0xff) << 8)
              | ((uint32_t)(xv.z & 0xff) << 16) | ((uint32_t)(xv.w & 0xff) << 24);
    }
    for (int idx = t; idx < NAA * NAA; idx += 512)
        Vs[idx] = V[h * (NAA * NAA) + idx];

    f32x4 acc[2][4];
#pragma unroll
    for (int fm = 0; fm < 2; ++fm)
#pragma unroll
        for (int fn = 0; fn < 4; ++fn)
            acc[fm][fn] = (f32x4){0.f, 0.f, 0.f, 0.f};

    const uint16_t* Eb = (const uint16_t*)Ew + ((size_t)h * NL + it * BM) * NL;

    __syncthreads();   // xs ready for B-gen

    for (int kc = 0; kc < 8; ++kc) {
        // ---- stage A chunk: rows 0..63, k = kc*64 .. +63, XOR-swizzled
        {
            int ai = t >> 3, seg = t & 7;
            uint4 av = *(const uint4*)(Eb + (size_t)ai * NL + kc * BK + seg * 8);
            uint32_t ba = (uint32_t)(ai * 128 + seg * 16) ^ (uint32_t)((ai & 7) << 4);
            *(uint4*)(As + ba) = av;
        }
        // ---- generate one-hot B chunk: Bs[n][k], n = bb*32+c, XOR-swizzled
        {
            int n = t & 255, kh = t >> 8;        // kh: which 32-k half
            int bb = n >> 5, c = n & 31;
            uint32_t xw[8];
#pragma unroll
            for (int q = 0; q < 8; ++q)
                xw[q] = xs[bb * 128 + kc * 16 + kh * 8 + q];   // broadcast reads
            uint32_t ow[16];
#pragma unroll
            for (int m = 0; m < 16; ++m) {
                uint32_t w = xw[m >> 1];
                uint32_t b0 = (w >> ((m & 1) * 16)) & 0xffu;
                uint32_t b1 = (w >> ((m & 1) * 16 + 8)) & 0xffu;
                ow[m] = ((b0 == (uint32_t)c) ? 0x3F80u : 0u)
                      | ((b1 == (uint32_t)c) ? 0x3F800000u : 0u);
            }
            uint32_t bbase = (uint32_t)(n * 128 + kh * 64);
            uint32_t sw = (uint32_t)((n & 7) << 4);
#pragma unroll
            for (int q = 0; q < 4; ++q) {
                uint4 w4;
                w4.x = ow[4 * q]; w4.y = ow[4 * q + 1];
                w4.z = ow[4 * q + 2]; w4.w = ow[4 * q + 3];
                *(uint4*)(Bs + ((bbase + (uint32_t)(q * 16)) ^ sw)) = w4;
            }
        }
        __syncthreads();
        // ---- MFMA over this chunk (2 k-steps of 32)
#pragma unroll
        for (int ks = 0; ks < 2; ++ks) {
            bf16x8 af[2], bfr[4];
#pragma unroll
            for (int fm = 0; fm < 2; ++fm) {
                int row = wm * 32 + fm * 16 + (lane & 15);
                uint32_t ba = (uint32_t)(row * 128 + (ks * 32 + (lane >> 4) * 8) * 2)
                            ^ (uint32_t)((row & 7) << 4);
                af[fm] = *(bf16x8*)(As + ba);
            }
#pragma unroll
            for (int fn = 0; fn < 4; ++fn) {
                int col = wn * 64 + fn * 16 + (lane & 15);
                uint32_t ba = (uint32_t)(col * 128 + (ks * 32 + (lane >> 4) * 8) * 2)
                            ^ (uint32_t)((col & 7) << 4);
                bfr[fn] = *(bf16x8*)(Bs + ba);
            }
#pragma unroll
            for (int fm = 0; fm < 2; ++fm)
#pragma unroll
                for (int fn = 0; fn < 4; ++fn)
                    acc[fm][fn] = __builtin_amdgcn_mfma_f32_16x16x32_bf16(
                        af[fm], bfr[fn], acc[fm][fn], 0, 0, 0);
        }
        __syncthreads();
    }

    // ---- acc -> LDS, stride 257 floats (bank = (i + col) % 32)
    float* Racc = (float*)(smem + ACC_OFF);
#pragma unroll
    for (int fm = 0; fm < 2; ++fm) {
#pragma unroll
        for (int fn = 0; fn < 4; ++fn) {
            int col = wn * 64 + fn * 16 + (lane & 15);
            int rbase = wm * 32 + fm * 16 + (lane >> 4) * 4;
#pragma unroll
            for (int r = 0; r < 4; ++r)
                Racc[(rbase + r) * 257 + col] = acc[fm][fn][r];
        }
    }
    __syncthreads();

    // ---- dot with V row, scale by 1/Z, reduce, accumulate energy
    {
        int bb = wv;                 // wave = batch within tile
        int i  = lane;               // lane = row within tile
        int ig = it * BM + i;
        uint32_t xwrd = xs[bb * 128 + (ig >> 2)];
        int a = (int)((xwrd >> ((ig & 3) * 8)) & 0xffu);
        const float* vrow = Vs + a * NAA;
        const float* rrow = Racc + i * 257 + bb * 32;
        float dot = 0.f;
#pragma unroll
        for (int c = 0; c < NAA; ++c) dot += vrow[c] * rrow[c];
        float val = dot / Zg[(size_t)h * NL + ig];
#pragma unroll
        for (int off = 32; off > 0; off >>= 1) val += __shfl_xor(val, off);
        if (lane == 0) atomicAdd(&out[bt * 8 + bb], -val);
    }
}

// ---------------------------------------------------------------------------
extern "C" void kernel_launch(void* const* d_in, const int* in_sizes, int n_in,
                              void* d_out, int out_size, void* d_ws, size_t ws_size,
                              hipStream_t stream) {
    const int*   x = (const int*)d_in[0];
    const float* Q = (const float*)d_in[1];
    const float* K = (const float*)d_in[2];
    const float* V = (const float*)d_in[3];
    float* out = (float*)d_out;
    uint8_t* ws = (uint8_t*)d_ws;

    uint32_t* Ew = (uint32_t*)(ws + EW_OFF);
    float*    Kt = (float*)(ws + KT_OFF);
    float*    Zg = (float*)(ws + ZG_OFF);

    hipMemsetAsync(d_out, 0, NB * sizeof(float), stream);
    prep_kt<<<2048, 256, 0, stream>>>(K, Kt);
    scores_exp<<<2048, 256, 0, stream>>>(Q, Kt, Ew, Zg);
    (void)hipFuncSetAttribute((const void*)gemm_energy,
                              hipFuncAttributeMaxDynamicSharedMemorySize, LDS_TOT);
    gemm_energy<<<2048, 512, LDS_TOT, stream>>>(Ew, x, Zg, V, out);
}

// Round 3
// 126.395 us; speedup vs baseline: 21.6115x; 1.3730x over previous
//
#include <hip/hip_runtime.h>
#include <hip/hip_bf16.h>
#include <stdint.h>

// Problem constants (B=64, L=512, H=32, D=128, 21 amino acids)
#define NH   32
#define NL   512
#define ND   128
#define NB   64
#define NAA  21

// ws layout:
//   Ewsw: bf16[...]  NORMALIZED attention A[h,i,j], stored as pre-swizzled
//         8KB tiles [h][it64 0..7][kc 0..7][64 rows x 64 k]          16 MB @ 0
//   Kt  : float [NH*32*NL*4] K transposed [h][d4][j][4]               8 MB @ 16MB
//   Bg  : bf16 one-hot, pre-swizzled 32KB tiles [bt 0..7][kc 0..7]
//         [n=256 x k=64],  n = bb*32 + c                              2 MB @ 24MB
#define EW_OFF  0
#define KT_OFF  (16u << 20)
#define BG_OFF  (24u << 20)

typedef short   bf16x8 __attribute__((ext_vector_type(8)));
typedef float   f32x4  __attribute__((ext_vector_type(4)));

__device__ __forceinline__ uint32_t bf16rtn(float f) {
    uint32_t u = __float_as_uint(f);
    return (u + 0x7fffu + ((u >> 16) & 1u)) >> 16;
}

__device__ __forceinline__ void gl16(const void* g, void* l) {
    __builtin_amdgcn_global_load_lds(
        (const __attribute__((address_space(1))) uint32_t*)g,
        (__attribute__((address_space(3))) uint32_t*)l, 16, 0, 0);
}

// swizzled byte offset within a 64-row tile: rows r, bf16 column kk
// byte = (r*128 + kk*2) ^ ((r&7)<<4)

// ---------------------------------------------------------------------------
// K transpose: Kt[(h*32+d4)*512 + j][0..3] = K[h][j][d4*4 .. d4*4+3]
__global__ void prep_kt(const float* __restrict__ K, float* __restrict__ Kt) {
    int tid = blockIdx.x * 256 + threadIdx.x;
    int d4 = tid & 31;
    int j  = (tid >> 5) & 511;
    int h  = tid >> 14;
    float4 v = *(const float4*)(K + (((size_t)h * NL + j) * ND + d4 * 4));
    *(float4*)(Kt + (((size_t)h * 32 + d4) * NL + j) * 4) = v;
}

// ---------------------------------------------------------------------------
// One-hot B, pre-swizzled.  Bg tile (bt,kc): n in [0,256), k in [0,64).
// thread -> one u32 (bf16 pair, k=2s,2s+1).  Lanes: s fastest -> coalesced.
__global__ void prep_onehot(const int* __restrict__ x, uint32_t* __restrict__ Bg) {
    int tid = blockIdx.x * 256 + threadIdx.x;    // 19 bits
    int s  = tid & 31;
    int n  = (tid >> 5) & 255;
    int kc = (tid >> 13) & 7;
    int bt = tid >> 16;
    int b = bt * 8 + (n >> 5);
    int c = n & 31;
    int k = kc * 64 + 2 * s;
    int2 xv = *(const int2*)(x + (size_t)b * NL + k);
    uint32_t val = ((xv.x == c) ? 0x3F80u : 0u) | ((xv.y == c) ? 0x3F800000u : 0u);
    uint32_t ub = ((uint32_t)(n * 128 + s * 4)) ^ (uint32_t)((n & 7) << 4);
    Bg[((size_t)(bt * 8 + kc) << 13) + (ub >> 2)] = val;
}

// ---------------------------------------------------------------------------
// scores + exp + row-normalize: block = (h, 8 rows), 256 threads,
// thread owns j = 2t, 2t+1.  Writes normalized bf16 pairs to the swizzled
// tile layout consumed by gemm_energy's global_load_lds.
__global__ void scores_exp(const float* __restrict__ Q, const float* __restrict__ Kt,
                           uint32_t* __restrict__ Ewsw) {
    int h  = blockIdx.x >> 6;
    int i0 = (blockIdx.x & 63) * 8;
    int t  = threadIdx.x;
    const float4* kt = (const float4*)Kt + (size_t)h * (32 * NL);
    const float*  qb = Q + ((size_t)h * NL + i0) * ND;

    float acc0[8], acc1[8];
#pragma unroll
    for (int ii = 0; ii < 8; ++ii) { acc0[ii] = 0.f; acc1[ii] = 0.f; }

    for (int d4 = 0; d4 < 32; ++d4) {
        float4 k1 = kt[d4 * NL + 2 * t];
        float4 k2 = kt[d4 * NL + 2 * t + 1];
#pragma unroll
        for (int ii = 0; ii < 8; ++ii) {
            float4 q = *(const float4*)(qb + ii * ND + d4 * 4);  // block-uniform
            acc0[ii] += q.x * k1.x + q.y * k1.y + q.z * k1.z + q.w * k1.w;
            acc1[ii] += q.x * k2.x + q.y * k2.y + q.z * k2.z + q.w * k2.w;
        }
    }

    __shared__ float zp[4][8];
    int lane = t & 63, wv = t >> 6;
#pragma unroll
    for (int ii = 0; ii < 8; ++ii) {
        acc0[ii] = __expf(acc0[ii] * 0.0078125f);   // scores = dot/128
        acc1[ii] = __expf(acc1[ii] * 0.0078125f);
        float z = acc0[ii] + acc1[ii];
#pragma unroll
        for (int off = 32; off > 0; off >>= 1) z += __shfl_xor(z, off);
        if (lane == 0) zp[wv][ii] = z;
    }
    __syncthreads();

    int it64 = i0 >> 6;
    int kc   = t >> 5;
    uint32_t colb = (uint32_t)((t & 31) * 4);
#pragma unroll
    for (int ii = 0; ii < 8; ++ii) {
        float rinv = 1.0f / (zp[0][ii] + zp[1][ii] + zp[2][ii] + zp[3][ii]);
        uint32_t val = bf16rtn(acc0[ii] * rinv) | (bf16rtn(acc1[ii] * rinv) << 16);
        int r = (i0 & 63) + ii;
        uint32_t ub = ((uint32_t)(r * 128) + colb) ^ (uint32_t)((r & 7) << 4);
        Ewsw[(((size_t)(h * 8 + it64) * 8 + kc) << 11) + (ub >> 2)] = val;
    }
}

// ---------------------------------------------------------------------------
// GEMM + epilogue.  Block = (h, it of 128 rows, bt of 8 batches).
//   R[i, bb*32+c] = sum_k A[h,i,k] * [x[bt*8+bb,k]==c]    (bf16 MFMA)
//   energy -= sum_c R[i,bb,c] * V[h, x[b,i], c]           (A pre-normalized)
// m97 structure: global_load_lds(16B) staging of pre-swizzled tiles,
// 2-barrier K-loop, 8 waves as 2(M)x4(N), 4x4 acc per wave.
#define AS_OFF  0          // 2 x 8KB subtiles (rows 0..63 / 64..127)
#define BS_OFF  16384      // 32KB (n=256 x k=64)
#define RACC_OFF 0         // 64*257*4 = 65792 (epilogue, reuses tile space)
#define XS_OFF  65792      // 1024 u32 packed x bytes
#define VS_OFF  69888      // 441 f32
#define LDS_TOT 71680

__global__ __launch_bounds__(512, 2)
void gemm_energy(const uint8_t* __restrict__ Ewswb, const uint8_t* __restrict__ Bgb,
                 const int* __restrict__ x, const float* __restrict__ V,
                 float* __restrict__ out) {
    extern __shared__ uint8_t smem[];
    uint8_t*  As = smem + AS_OFF;
    uint8_t*  Bs = smem + BS_OFF;
    float*    Racc = (float*)(smem + RACC_OFF);
    uint32_t* xs = (uint32_t*)(smem + XS_OFF);
    float*    Vs = (float*)(smem + VS_OFF);

    // XCD-grouping swizzle: the 8 bt-blocks sharing an A-panel get bids
    // congruent mod 8 -> same XCD L2.
    int bid = blockIdx.x;
    int bt = (bid >> 3) & 7;
    int g  = ((bid >> 6) << 3) | (bid & 7);   // (h,it) group, 0..127
    int h  = g >> 2;
    int it = g & 3;

    int t = threadIdx.x, lane = t & 63, wv = t >> 6;
    int wm = wv >> 2, wn = wv & 3;            // 2(M) x 4(N)

    // stage x bytes (epilogue) + V
    for (int w = t; w < 1024; w += 512) {
        int bb = w >> 7;
        int k4 = (w & 127) * 4;
        int4 xv = *(const int4*)(x + (size_t)(bt * 8 + bb) * NL + k4);
        xs[w] = (uint32_t)(xv.x & 0xff) | ((uint32_t)(xv.y & 0xff) << 8)
              | ((uint32_t)(xv.z & 0xff) << 16) | ((uint32_t)(xv.w & 0xff) << 24);
    }
    for (int idx = t; idx < NAA * NAA; idx += 512)
        Vs[idx] = V[h * (NAA * NAA) + idx];

    f32x4 acc[4][4];
#pragma unroll
    for (int fm = 0; fm < 4; ++fm)
#pragma unroll
        for (int fn = 0; fn < 4; ++fn)
            acc[fm][fn] = (f32x4){0.f, 0.f, 0.f, 0.f};

    const uint8_t* Abase = Ewswb + (((size_t)(h * 8 + it * 2) * 8) << 13);
    const uint8_t* Bbase = Bgb + ((size_t)(bt * 8) << 15);

    for (int kc = 0; kc < 8; ++kc) {
        // stage A (two 8KB subtiles) + B (32KB), all pre-swizzled, linear LDS
        {
            const uint8_t* asrc = Abase + ((size_t)kc << 13) + t * 16;
            gl16(asrc,             As + t * 16);
            gl16(asrc + (8 << 13), As + 8192 + t * 16);
            const uint8_t* bsrc = Bbase + ((size_t)kc << 15) + t * 16;
#pragma unroll
            for (int q = 0; q < 4; ++q)
                gl16(bsrc + q * 8192, Bs + q * 8192 + t * 16);
        }
        __syncthreads();
#pragma unroll
        for (int ks = 0; ks < 2; ++ks) {
            int kb = (ks * 32 + (lane >> 4) * 8) * 2;
            bf16x8 af[4], bfr[4];
#pragma unroll
            for (int fm = 0; fm < 4; ++fm) {
                int rr = fm * 16 + (lane & 15);
                af[fm] = *(bf16x8*)(As + wm * 8192 +
                           ((uint32_t)(rr * 128 + kb) ^ (uint32_t)((rr & 7) << 4)));
            }
#pragma unroll
            for (int fn = 0; fn < 4; ++fn) {
                int nn = wn * 64 + fn * 16 + (lane & 15);
                bfr[fn] = *(bf16x8*)(Bs +
                           ((uint32_t)(nn * 128 + kb) ^ (uint32_t)((nn & 7) << 4)));
            }
#pragma unroll
            for (int fm = 0; fm < 4; ++fm)
#pragma unroll
                for (int fn = 0; fn < 4; ++fn)
                    acc[fm][fn] = __builtin_amdgcn_mfma_f32_16x16x32_bf16(
                        af[fm], bfr[fn], acc[fm][fn], 0, 0, 0);
        }
        __syncthreads();
    }

    // ---- epilogue: two 64-row halves through Racc (stride 257: conflict-free)
    float val = 0.f;
#pragma unroll
    for (int half = 0; half < 2; ++half) {
        if (wm == half) {
#pragma unroll
            for (int fm = 0; fm < 4; ++fm) {
#pragma unroll
                for (int fn = 0; fn < 4; ++fn) {
                    int col = wn * 64 + fn * 16 + (lane & 15);
                    int rbase = fm * 16 + (lane >> 4) * 4;
#pragma unroll
                    for (int r = 0; r < 4; ++r)
                        Racc[(rbase + r) * 257 + col] = acc[fm][fn][r];
                }
            }
        }
        __syncthreads();
        int ig = it * 128 + half * 64 + lane;
        uint32_t xw = xs[wv * 128 + (ig >> 2)];
        int a = (int)((xw >> ((ig & 3) * 8)) & 0xffu);
        const float* vrow = Vs + a * NAA;
        const float* rrow = Racc + lane * 257 + wv * 32;
        float dot = 0.f;
#pragma unroll
        for (int c = 0; c < NAA; ++c) dot += vrow[c] * rrow[c];
        val += dot;
        __syncthreads();
    }
#pragma unroll
    for (int off = 32; off > 0; off >>= 1) val += __shfl_xor(val, off);
    if (lane == 0) atomicAdd(&out[bt * 8 + wv], -val);
}

// ---------------------------------------------------------------------------
extern "C" void kernel_launch(void* const* d_in, const int* in_sizes, int n_in,
                              void* d_out, int out_size, void* d_ws, size_t ws_size,
                              hipStream_t stream) {
    const int*   x = (const int*)d_in[0];
    const float* Q = (const float*)d_in[1];
    const float* K = (const float*)d_in[2];
    const float* V = (const float*)d_in[3];
    float* out = (float*)d_out;
    uint8_t* ws = (uint8_t*)d_ws;

    uint32_t* Ewsw = (uint32_t*)(ws + EW_OFF);
    float*    Kt   = (float*)(ws + KT_OFF);
    uint32_t* Bg   = (uint32_t*)(ws + BG_OFF);

    hipMemsetAsync(d_out, 0, NB * sizeof(float), stream);
    prep_kt<<<2048, 256, 0, stream>>>(K, Kt);
    prep_onehot<<<2048, 256, 0, stream>>>(x, Bg);
    scores_exp<<<2048, 256, 0, stream>>>(Q, Kt, Ewsw);
    (void)hipFuncSetAttribute((const void*)gemm_energy,
                              hipFuncAttributeMaxDynamicSharedMemorySize, LDS_TOT);
    gemm_energy<<<1024, 512, LDS_TOT, stream>>>((const uint8_t*)Ewsw, (const uint8_t*)Bg,
                                                x, V, out);
}

// Round 4
// 103.586 us; speedup vs baseline: 26.3701x; 1.2202x over previous
//
#include <hip/hip_runtime.h>
#include <hip/hip_bf16.h>
#include <stdint.h>

// Problem constants (B=64, L=512, H=32, D=128, 21 amino acids)
#define NH  32
#define NL  512
#define ND  128
#define NB  64
#define NAA 21

// ws layout:
//   Ewsw: bf16 exp(scores) UNNORMALIZED, swizzled 8KB tiles [h][it64][kc]  16 MB @ 0
//   Qb/Kb: bf16 swizzled 8KB tiles [h][pt 0..7][dc 0..1] (64 pos x 64 d)   2 MB each
//   Zg  : f32 row sums [h][i]                                              64 KB
#define EW_OFF 0
#define QB_OFF (16u << 20)
#define KB_OFF (18u << 20)
#define ZG_OFF (20u << 20)

typedef short bf16x8 __attribute__((ext_vector_type(8)));
typedef float f32x4  __attribute__((ext_vector_type(4)));

static __device__ __forceinline__ uint32_t bf16rtn(float f) {
    uint32_t u = __float_as_uint(f);
    return (u + 0x7fffu + ((u >> 16) & 1u)) >> 16;
}
static __device__ __forceinline__ void gl16(const void* g, void* l) {
    __builtin_amdgcn_global_load_lds(
        (const __attribute__((address_space(1))) uint32_t*)g,
        (__attribute__((address_space(3))) uint32_t*)l, 16, 0, 0);
}
// swizzled byte within a 64x64 bf16 tile: (r*128 + kk*2) ^ ((r&7)<<4)

// ---------------------------------------------------------------------------
// Q,K f32 -> bf16 swizzled tiles.  2^21 threads: bit20 selects Q/K.
__global__ void prep_qk(const float* __restrict__ Q, const float* __restrict__ K,
                        uint32_t* __restrict__ Qb, uint32_t* __restrict__ Kb) {
    uint32_t tid = blockIdx.x * 256 + threadIdx.x;
    const float* src = (tid >> 20) ? K : Q;
    uint32_t*    dst = (tid >> 20) ? Kb : Qb;
    uint32_t p = tid & 0xFFFFFu;
    uint32_t kk2 = p & 31, r = (p >> 5) & 63, dc = (p >> 11) & 1;
    uint32_t pt = (p >> 12) & 7, h = p >> 15;
    uint32_t pos = pt * 64 + r, d0 = dc * 64 + kk2 * 2;
    float2 v = *(const float2*)(src + ((size_t)(h * NL + pos) * ND + d0));
    uint32_t val = bf16rtn(v.x) | (bf16rtn(v.y) << 16);
    uint32_t byte = (r * 128 + kk2 * 4) ^ ((r & 7) << 4);
    dst[((((h * 8 + pt) * 2 + dc)) << 11) + (byte >> 2)] = val;
}

// ---------------------------------------------------------------------------
// scores via MFMA, SWAPPED operands: S^T = K(j rows) x Q(i cols) over d=128.
// Lane then holds 4 consecutive j for fixed i -> in-lane bf16-pair pack into
// the swizzled Ewsw tiles.  Z[i] accumulated in f32, written to Zg.
#define SC_QS 0        // 16KB: Q tiles dc=0,1
#define SC_KS 16384    // 32KB: K subchunk tiles q = jt*2+dc
#define SC_ZS 49152    // 64 f32
#define SC_TOT 49408

__global__ __launch_bounds__(512)
void scores_mfma(const uint8_t* __restrict__ Qb, const uint8_t* __restrict__ Kb,
                 uint8_t* __restrict__ Ewsw, float* __restrict__ Zg) {
    extern __shared__ uint8_t smem[];
    int h = blockIdx.x >> 3, it = blockIdx.x & 7;
    int t = threadIdx.x, lane = t & 63, wv = t >> 6;
    int wm = wv >> 1, wn = wv & 1;   // 4(Mj) x 2(Ni)

    const uint8_t* qsrc = Qb + (((size_t)(h * 8 + it) * 2) << 13);
    gl16(qsrc + t * 16,        smem + SC_QS + t * 16);
    gl16(qsrc + 8192 + t * 16, smem + SC_QS + 8192 + t * 16);
    if (t < 64) *(float*)(smem + SC_ZS + t * 4) = 0.f;

    float zp[2] = {0.f, 0.f};
    for (int sc = 0; sc < 4; ++sc) {
        __syncthreads();   // prev compute done reading Ks (and 1st: covers Q/Zs)
        const uint8_t* ksrc = Kb + (((size_t)(h * 8 + sc * 2) * 2) << 13);
#pragma unroll
        for (int q = 0; q < 4; ++q)
            gl16(ksrc + q * 8192 + t * 16, smem + SC_KS + q * 8192 + t * 16);
        __syncthreads();   // implicit vmcnt(0): K staged

        f32x4 acc[2][2];
#pragma unroll
        for (int fm = 0; fm < 2; ++fm)
#pragma unroll
            for (int fn = 0; fn < 2; ++fn) acc[fm][fn] = (f32x4){0.f,0.f,0.f,0.f};

#pragma unroll
        for (int ks = 0; ks < 4; ++ks) {
            int kb = ((ks & 1) * 32 + (lane >> 4) * 8) * 2;
            int dc = ks >> 1;
            bf16x8 af[2], bfr[2];
#pragma unroll
            for (int fm = 0; fm < 2; ++fm) {
                int rr = wm * 32 + fm * 16 + (lane & 15);     // j in [0,128)
                int rt = rr >> 6, r6 = rr & 63;
                af[fm] = *(bf16x8*)(smem + SC_KS + (rt * 2 + dc) * 8192 +
                          (((uint32_t)(r6 * 128 + kb)) ^ ((r6 & 7) << 4)));
            }
#pragma unroll
            for (int fn = 0; fn < 2; ++fn) {
                int rr = wn * 32 + fn * 16 + (lane & 15);     // i in [0,64)
                bfr[fn] = *(bf16x8*)(smem + SC_QS + dc * 8192 +
                          (((uint32_t)(rr * 128 + kb)) ^ ((rr & 7) << 4)));
            }
#pragma unroll
            for (int fm = 0; fm < 2; ++fm)
#pragma unroll
                for (int fn = 0; fn < 2; ++fn)
                    acc[fm][fn] = __builtin_amdgcn_mfma_f32_16x16x32_bf16(
                        af[fm], bfr[fn], acc[fm][fn], 0, 0, 0);
        }
        // exp, Z partials, pack pairs, store to swizzled tile
#pragma unroll
        for (int fm = 0; fm < 2; ++fm)
#pragma unroll
            for (int fn = 0; fn < 2; ++fn) {
                float e0 = __expf(acc[fm][fn][0] * 0.0078125f);
                float e1 = __expf(acc[fm][fn][1] * 0.0078125f);
                float e2 = __expf(acc[fm][fn][2] * 0.0078125f);
                float e3 = __expf(acc[fm][fn][3] * 0.0078125f);
                zp[fn] += (e0 + e1) + (e2 + e3);
                uint2 pk;
                pk.x = bf16rtn(e0) | (bf16rtn(e1) << 16);
                pk.y = bf16rtn(e2) | (bf16rtn(e3) << 16);
                int j = sc * 128 + wm * 32 + fm * 16 + (lane >> 4) * 4;
                int i = wn * 32 + fn * 16 + (lane & 15);
                int kc = j >> 6, kk = j & 63;
                uint32_t byte = ((uint32_t)(i * 128 + kk * 2)) ^ ((uint32_t)((i & 7) << 4));
                *(uint2*)(Ewsw + (((size_t)((h * 8 + it) * 8 + kc)) << 13) + byte) = pk;
            }
    }
    zp[0] += __shfl_xor(zp[0], 16); zp[0] += __shfl_xor(zp[0], 32);
    zp[1] += __shfl_xor(zp[1], 16); zp[1] += __shfl_xor(zp[1], 32);
    if (lane < 16) {
        atomicAdd((float*)(smem + SC_ZS) + wn * 32 + lane,      zp[0]);
        atomicAdd((float*)(smem + SC_ZS) + wn * 32 + 16 + lane, zp[1]);
    }
    __syncthreads();
    if (t < 64) Zg[(size_t)h * NL + it * 64 + t] = *((float*)(smem + SC_ZS) + t);
}

// ---------------------------------------------------------------------------
// Energy GEMM.  Block = (g=(h,it of 128 rows), nb of 192 cols), n = b*21+c
// (N=1344, no padding).  A staged via gl16 (dbuf, 2-phase overlap); one-hot B
// generated IN REGISTERS from x codes.  Epilogue: Racc->LDS stride 193,
// partial-c dots vs V, /Z, wave-reduce, atomicAdd.
#define GE_XS   0       // 10*129 u32 = 5160 -> 5248
#define GE_VS   5248    // 441 f32 -> pad to 7168
#define GE_AB   7168    // 2 x 16384 (A dbuf)
#define GE_RACC 7168    // 64*193*4 = 49408 (epilogue reuse) -> end 56576
#define GE_TOT  56576

__global__ __launch_bounds__(512, 4)
void gemm_energy(const uint8_t* __restrict__ Ew, const int* __restrict__ x,
                 const float* __restrict__ Zg, const float* __restrict__ V,
                 float* __restrict__ out) {
    extern __shared__ uint8_t smem[];
    uint32_t* xs = (uint32_t*)(smem + GE_XS);
    float*    Vs = (float*)(smem + GE_VS);
    float*    Racc = (float*)(smem + GE_RACC);

    // XCD swizzle: 7 nb-replicas of a (h,it) panel share bid mod 8.
    int bid = blockIdx.x;
    int xcd = bid & 7, q = bid >> 3;
    int nb = q % 7, g = (q / 7) * 8 + xcd;   // g in [0,128)
    int h = g >> 2, it = g & 3;
    int n0 = nb * 192;
    int bstart = n0 / 21;
    int bend = (n0 + 191) / 21;
    int bcnt = bend - bstart + 1;            // 9 or 10

    int t = threadIdx.x, lane = t & 63, wv = t >> 6;
    int wm = wv >> 2, wn = wv & 3;           // 2(M) x 4(N)

    for (int idx = t; idx < bcnt * 128; idx += 512) {
        int s = idx >> 7, w = idx & 127;
        int4 xv = *(const int4*)(x + (size_t)(bstart + s) * NL + w * 4);
        xs[s * 129 + w] = (uint32_t)(xv.x & 0xff) | ((uint32_t)(xv.y & 0xff) << 8)
                        | ((uint32_t)(xv.z & 0xff) << 16) | ((uint32_t)(xv.w & 0xff) << 24);
    }
    for (int idx = t; idx < NAA * NAA; idx += 512) Vs[idx] = V[h * (NAA * NAA) + idx];

    int ccol[3], slotc[3];
#pragma unroll
    for (int fn = 0; fn < 3; ++fn) {
        int n = n0 + wn * 48 + fn * 16 + (lane & 15);
        int b = n / 21;
        ccol[fn] = n - b * 21;
        slotc[fn] = b - bstart;
    }

    f32x4 acc[4][3];
#pragma unroll
    for (int fm = 0; fm < 4; ++fm)
#pragma unroll
        for (int fn = 0; fn < 3; ++fn) acc[fm][fn] = (f32x4){0.f,0.f,0.f,0.f};

    const uint8_t* A0 = Ew + (((size_t)(h * 8 + it * 2) * 8) << 13);
    const uint8_t* A1 = Ew + (((size_t)(h * 8 + it * 2 + 1) * 8) << 13);

#define GE_STAGE(p, kc) do { \
        gl16(A0 + (((size_t)(kc)) << 13) + t * 16, smem + GE_AB + (p) * 16384 + t * 16); \
        gl16(A1 + (((size_t)(kc)) << 13) + t * 16, smem + GE_AB + (p) * 16384 + 8192 + t * 16); \
    } while (0)

    GE_STAGE(0, 0);
    __syncthreads();   // implicit vmcnt(0): buf0 ready (also xs/Vs visible)

    for (int kc = 0; kc < 8; ++kc) {
        int p = kc & 1;
        if (kc < 7) GE_STAGE(p ^ 1, kc + 1);   // overlaps with compute below
#pragma unroll
        for (int ks = 0; ks < 2; ++ks) {
            int kb = (ks * 32 + (lane >> 4) * 8) * 2;
            bf16x8 af[4];
#pragma unroll
            for (int fm = 0; fm < 4; ++fm) {
                int rr = wm * 64 + fm * 16 + (lane & 15);
                int rt = rr >> 6, r6 = rr & 63;
                af[fm] = *(bf16x8*)(smem + GE_AB + p * 16384 + rt * 8192 +
                          (((uint32_t)(r6 * 128 + kb)) ^ ((r6 & 7) << 4)));
            }
            int k0w = kc * 16 + ks * 8 + (lane >> 4) * 2;
            bf16x8 bfr[3];
#pragma unroll
            for (int fn = 0; fn < 3; ++fn) {
                uint32_t w0 = xs[slotc[fn] * 129 + k0w];
                uint32_t w1 = xs[slotc[fn] * 129 + k0w + 1];
                uint32_t c = (uint32_t)ccol[fn];
                union { uint32_t u[4]; bf16x8 v; } pk;
#pragma unroll
                for (int pq = 0; pq < 4; ++pq) {
                    uint32_t w = (pq < 2) ? w0 : w1;
                    uint32_t sh = (pq & 1) * 16;
                    uint32_t b0 = (w >> sh) & 0xffu, b1 = (w >> (sh + 8)) & 0xffu;
                    pk.u[pq] = ((b0 == c) ? 0x3F80u : 0u) | ((b1 == c) ? 0x3F800000u : 0u);
                }
                bfr[fn] = pk.v;
            }
#pragma unroll
            for (int fm = 0; fm < 4; ++fm)
#pragma unroll
                for (int fn = 0; fn < 3; ++fn)
                    acc[fm][fn] = __builtin_amdgcn_mfma_f32_16x16x32_bf16(
                        af[fm], bfr[fn], acc[fm][fn], 0, 0, 0);
        }
        __syncthreads();   // drains next-stage gl16 (vmcnt 0) + orders buf reuse
    }

    // ---- epilogue
    float esum[2] = {0.f, 0.f};
#pragma unroll
    for (int half = 0; half < 2; ++half) {
        if (wm == half) {
#pragma unroll
            for (int fm = 0; fm < 4; ++fm)
#pragma unroll
                for (int fn = 0; fn < 3; ++fn) {
                    int col = wn * 48 + fn * 16 + (lane & 15);
                    int rb = fm * 16 + (lane >> 4) * 4;
#pragma unroll
                    for (int r = 0; r < 4; ++r)
                        Racc[(rb + r) * 193 + col] = acc[fm][fn][r];
                }
        }
        __syncthreads();
        int ig = it * 128 + half * 64 + lane;
        float rz = 1.0f / Zg[(size_t)h * NL + ig];
        for (int s = wv; s < bcnt; s += 8) {
            int b = bstart + s;
            uint32_t xw = xs[s * 129 + (ig >> 2)];
            int a = (int)((xw >> ((ig & 3) * 8)) & 0xffu);
            int off = b * 21 - n0;
            int clo = off < 0 ? -off : 0;
            int chi = (192 - off) < 21 ? (192 - off) : 21;
            float dot = 0.f;
            for (int c = clo; c < chi; ++c)
                dot += Vs[a * NAA + c] * Racc[lane * 193 + off + c];
            esum[s >> 3] += dot * rz;
        }
        __syncthreads();
    }
#pragma unroll
    for (int si = 0; si < 2; ++si) {
        float v = esum[si];
#pragma unroll
        for (int o = 32; o > 0; o >>= 1) v += __shfl_xor(v, o);
        int s = wv + si * 8;
        if (lane == 0 && s < bcnt) atomicAdd(&out[bstart + s], -v);
    }
}

// ---------------------------------------------------------------------------
extern "C" void kernel_launch(void* const* d_in, const int* in_sizes, int n_in,
                              void* d_out, int out_size, void* d_ws, size_t ws_size,
                              hipStream_t stream) {
    const int*   x = (const int*)d_in[0];
    const float* Q = (const float*)d_in[1];
    const float* K = (const float*)d_in[2];
    const float* V = (const float*)d_in[3];
    float* out = (float*)d_out;
    uint8_t* ws = (uint8_t*)d_ws;

    uint8_t*  Ewsw = ws + EW_OFF;
    uint32_t* Qb   = (uint32_t*)(ws + QB_OFF);
    uint32_t* Kb   = (uint32_t*)(ws + KB_OFF);
    float*    Zg   = (float*)(ws + ZG_OFF);

    hipMemsetAsync(d_out, 0, NB * sizeof(float), stream);
    prep_qk<<<8192, 256, 0, stream>>>(Q, K, Qb, Kb);
    (void)hipFuncSetAttribute((const void*)scores_mfma,
                              hipFuncAttributeMaxDynamicSharedMemorySize, SC_TOT);
    scores_mfma<<<256, 512, SC_TOT, stream>>>((const uint8_t*)Qb, (const uint8_t*)Kb,
                                              Ewsw, Zg);
    (void)hipFuncSetAttribute((const void*)gemm_energy,
                              hipFuncAttributeMaxDynamicSharedMemorySize, GE_TOT);
    gemm_energy<<<896, 512, GE_TOT, stream>>>((const uint8_t*)Ewsw, x, Zg, V, out);
}

// Round 7
// 79.339 us; speedup vs baseline: 34.4292x; 1.3056x over previous
//
#include <hip/hip_runtime.h>
#include <hip/hip_bf16.h>
#include <stdint.h>

// Problem constants (B=64, L=512, H=32, D=128, 21 amino acids)
#define NH  32
#define NL  512
#define ND  128
#define NB  64
#define NAA 21

// ws layout:
//   Ewsw: bf16 exp(scores) UNNORMALIZED, swizzled 8KB tiles [h][it64][kc]  16 MB @ 0
//   Qb/Kb: bf16 swizzled 8KB tiles [h][pt 0..7][dc 0..1] (64 pos x 64 d)   2 MB each
//   Zg  : f32 row sums [h][i]                                              64 KB
#define EW_OFF 0
#define QB_OFF (16u << 20)
#define KB_OFF (18u << 20)
#define ZG_OFF (20u << 20)

typedef short bf16x8 __attribute__((ext_vector_type(8)));
typedef float f32x4  __attribute__((ext_vector_type(4)));

static __device__ __forceinline__ uint32_t bf16rtn(float f) {
    uint32_t u = __float_as_uint(f);
    return (u + 0x7fffu + ((u >> 16) & 1u)) >> 16;
}
static __device__ __forceinline__ void gl16(const void* g, void* l) {
    __builtin_amdgcn_global_load_lds(
        (const __attribute__((address_space(1))) uint32_t*)g,
        (__attribute__((address_space(3))) uint32_t*)l, 16, 0, 0);
}
// swizzled byte within a 64x64 bf16 tile: (r*128 + kk*2) ^ ((r&7)<<4)

// ---------------------------------------------------------------------------
// Q,K f32 -> bf16 swizzled tiles.  2^21 threads: bit20 selects Q/K.
__global__ void prep_qk(const float* __restrict__ Q, const float* __restrict__ K,
                        uint32_t* __restrict__ Qb, uint32_t* __restrict__ Kb) {
    uint32_t tid = blockIdx.x * 256 + threadIdx.x;
    const float* src = (tid >> 20) ? K : Q;
    uint32_t*    dst = (tid >> 20) ? Kb : Qb;
    uint32_t p = tid & 0xFFFFFu;
    uint32_t kk2 = p & 31, r = (p >> 5) & 63, dc = (p >> 11) & 1;
    uint32_t pt = (p >> 12) & 7, h = p >> 15;
    uint32_t pos = pt * 64 + r, d0 = dc * 64 + kk2 * 2;
    float2 v = *(const float2*)(src + ((size_t)(h * NL + pos) * ND + d0));
    uint32_t val = bf16rtn(v.x) | (bf16rtn(v.y) << 16);
    uint32_t byte = (r * 128 + kk2 * 4) ^ ((r & 7) << 4);
    dst[((((h * 8 + pt) * 2 + dc)) << 11) + (byte >> 2)] = val;
}

// ---------------------------------------------------------------------------
// scores via MFMA, SWAPPED operands: S^T = K(j rows) x Q(i cols) over d=128.
#define SC_QS 0        // 16KB: Q tiles dc=0,1
#define SC_KS 16384    // 32KB: K subchunk tiles q = jt*2+dc
#define SC_ZS 49152    // 64 f32
#define SC_TOT 49408

__global__ __launch_bounds__(512)
void scores_mfma(const uint8_t* __restrict__ Qb, const uint8_t* __restrict__ Kb,
                 uint8_t* __restrict__ Ewsw, float* __restrict__ Zg) {
    extern __shared__ uint8_t smem[];
    int h = blockIdx.x >> 3, it = blockIdx.x & 7;
    int t = threadIdx.x, lane = t & 63, wv = t >> 6;
    int wm = wv >> 1, wn = wv & 1;   // 4(Mj) x 2(Ni)

    const uint8_t* qsrc = Qb + (((size_t)(h * 8 + it) * 2) << 13);
    gl16(qsrc + t * 16,        smem + SC_QS + t * 16);
    gl16(qsrc + 8192 + t * 16, smem + SC_QS + 8192 + t * 16);
    if (t < 64) *(float*)(smem + SC_ZS + t * 4) = 0.f;

    float zp[2] = {0.f, 0.f};
    for (int sc = 0; sc < 4; ++sc) {
        __syncthreads();   // prev compute done reading Ks (and 1st: covers Q/Zs)
        const uint8_t* ksrc = Kb + (((size_t)(h * 8 + sc * 2) * 2) << 13);
#pragma unroll
        for (int q = 0; q < 4; ++q)
            gl16(ksrc + q * 8192 + t * 16, smem + SC_KS + q * 8192 + t * 16);
        __syncthreads();   // implicit vmcnt(0): K staged

        f32x4 acc[2][2];
#pragma unroll
        for (int fm = 0; fm < 2; ++fm)
#pragma unroll
            for (int fn = 0; fn < 2; ++fn) acc[fm][fn] = (f32x4){0.f,0.f,0.f,0.f};

#pragma unroll
        for (int ks = 0; ks < 4; ++ks) {
            int kb = ((ks & 1) * 32 + (lane >> 4) * 8) * 2;
            int dc = ks >> 1;
            bf16x8 af[2], bfr[2];
#pragma unroll
            for (int fm = 0; fm < 2; ++fm) {
                int rr = wm * 32 + fm * 16 + (lane & 15);     // j in [0,128)
                int rt = rr >> 6, r6 = rr & 63;
                af[fm] = *(bf16x8*)(smem + SC_KS + (rt * 2 + dc) * 8192 +
                          (((uint32_t)(r6 * 128 + kb)) ^ ((r6 & 7) << 4)));
            }
#pragma unroll
            for (int fn = 0; fn < 2; ++fn) {
                int rr = wn * 32 + fn * 16 + (lane & 15);     // i in [0,64)
                bfr[fn] = *(bf16x8*)(smem + SC_QS + dc * 8192 +
                          (((uint32_t)(rr * 128 + kb)) ^ ((rr & 7) << 4)));
            }
#pragma unroll
            for (int fm = 0; fm < 2; ++fm)
#pragma unroll
                for (int fn = 0; fn < 2; ++fn)
                    acc[fm][fn] = __builtin_amdgcn_mfma_f32_16x16x32_bf16(
                        af[fm], bfr[fn], acc[fm][fn], 0, 0, 0);
        }
        // exp, Z partials, pack pairs, store to swizzled tile
#pragma unroll
        for (int fm = 0; fm < 2; ++fm)
#pragma unroll
            for (int fn = 0; fn < 2; ++fn) {
                float e0 = __expf(acc[fm][fn][0] * 0.0078125f);
                float e1 = __expf(acc[fm][fn][1] * 0.0078125f);
                float e2 = __expf(acc[fm][fn][2] * 0.0078125f);
                float e3 = __expf(acc[fm][fn][3] * 0.0078125f);
                zp[fn] += (e0 + e1) + (e2 + e3);
                uint2 pk;
                pk.x = bf16rtn(e0) | (bf16rtn(e1) << 16);
                pk.y = bf16rtn(e2) | (bf16rtn(e3) << 16);
                int j = sc * 128 + wm * 32 + fm * 16 + (lane >> 4) * 4;
                int i = wn * 32 + fn * 16 + (lane & 15);
                int kc = j >> 6, kk = j & 63;
                uint32_t byte = ((uint32_t)(i * 128 + kk * 2)) ^ ((uint32_t)((i & 7) << 4));
                *(uint2*)(Ewsw + (((size_t)((h * 8 + it) * 8 + kc)) << 13) + byte) = pk;
            }
    }
    zp[0] += __shfl_xor(zp[0], 16); zp[0] += __shfl_xor(zp[0], 32);
    zp[1] += __shfl_xor(zp[1], 16); zp[1] += __shfl_xor(zp[1], 32);
    if (lane < 16) {
        atomicAdd((float*)(smem + SC_ZS) + wn * 32 + lane,      zp[0]);
        atomicAdd((float*)(smem + SC_ZS) + wn * 32 + 16 + lane, zp[1]);
    }
    __syncthreads();
    if (t < 64) Zg[(size_t)h * NL + it * 64 + t] = *((float*)(smem + SC_ZS) + t);
}

// ---------------------------------------------------------------------------
// Energy GEMM (R4-proven math + sync structure).  Block = (g=(h,it of 128
// rows), nb of 192 cols), n = b*21+c (N=1344 exact).  A: gl16 double-buffer,
// stage kc+1 at top, compute kc, one __syncthreads per kc.  B: one-hot
// expanded in-register from xs codes (LDS), exactly as the passing R4 build.
// LDS shrunk to 39.8KB via windowed 32-row epilogue -> 4 blocks/CU.
#define GE_AB   0        // 2 x 16384 A dbuf
#define GE_RACC 0        // 32*193*4 = 24704 (epilogue, reuses AB)
#define GE_XS   32768    // 10*129 u32 = 5160 -> 5248
#define GE_VS   38016    // 441 f32 = 1764
#define GE_TOT  39808

__global__ __launch_bounds__(512, 4)
void gemm_energy(const uint8_t* __restrict__ Ew, const int* __restrict__ x,
                 const float* __restrict__ Zg, const float* __restrict__ V,
                 float* __restrict__ out) {
    extern __shared__ uint8_t smem[];
    uint32_t* xs = (uint32_t*)(smem + GE_XS);
    float*    Vs = (float*)(smem + GE_VS);
    float*    Racc = (float*)(smem + GE_RACC);

    // XCD swizzle: 7 nb-replicas of a (h,it) panel share bid mod 8.
    int bid = blockIdx.x;
    int xcd = bid & 7, q = bid >> 3;
    int nb = q % 7, g = (q / 7) * 8 + xcd;   // g in [0,128)
    int h = g >> 2, it = g & 3;
    int n0 = nb * 192;
    int bstart = n0 / 21;
    int bend = (n0 + 191) / 21;
    int bcnt = bend - bstart + 1;            // 9 or 10

    int t = threadIdx.x, lane = t & 63, wv = t >> 6;
    int wm = wv >> 2, wn = wv & 3;           // 2(M) x 4(N)

    // ---- prologue staging: A chunk 0 (gl16), xs, Vs
    const uint8_t* A0 = Ew + (((size_t)(h * 8 + it * 2) * 8) << 13);
    const uint8_t* A1 = Ew + (((size_t)(h * 8 + it * 2 + 1) * 8) << 13);
#define GE_STAGE(p, kc) do { \
        gl16(A0 + (((size_t)(kc)) << 13) + t * 16, smem + GE_AB + (p) * 16384 + t * 16); \
        gl16(A1 + (((size_t)(kc)) << 13) + t * 16, smem + GE_AB + (p) * 16384 + 8192 + t * 16); \
    } while (0)
    GE_STAGE(0, 0);

    for (int idx = t; idx < bcnt * 128; idx += 512) {
        int s = idx >> 7, w = idx & 127;
        int4 xv = *(const int4*)(x + (size_t)(bstart + s) * NL + w * 4);
        xs[s * 129 + w] = (uint32_t)(xv.x & 0xff) | ((uint32_t)(xv.y & 0xff) << 8)
                        | ((uint32_t)(xv.z & 0xff) << 16) | ((uint32_t)(xv.w & 0xff) << 24);
    }
    for (int idx = t; idx < NAA * NAA; idx += 512) Vs[idx] = V[h * (NAA * NAA) + idx];

    int ccol[3], slotc[3];
#pragma unroll
    for (int fn = 0; fn < 3; ++fn) {
        int n = n0 + wn * 48 + fn * 16 + (lane & 15);
        int b = n / 21;
        ccol[fn] = n - b * 21;
        slotc[fn] = b - bstart;
    }

    f32x4 acc[4][3];
#pragma unroll
    for (int fm = 0; fm < 4; ++fm)
#pragma unroll
        for (int fn = 0; fn < 3; ++fn) acc[fm][fn] = (f32x4){0.f,0.f,0.f,0.f};

    __syncthreads();   // full drain: stage(0), xs, Vs ready

    for (int kc = 0; kc < 8; ++kc) {
        int p = kc & 1;
        if (kc < 7) GE_STAGE(p ^ 1, kc + 1);   // overlaps with compute below
#pragma unroll
        for (int ks = 0; ks < 2; ++ks) {
            int kb = (ks * 32 + (lane >> 4) * 8) * 2;
            bf16x8 af[4];
#pragma unroll
            for (int fm = 0; fm < 4; ++fm) {
                int r6 = fm * 16 + (lane & 15);
                af[fm] = *(bf16x8*)(smem + GE_AB + p * 16384 + wm * 8192 +
                          (((uint32_t)(r6 * 128 + kb)) ^ ((r6 & 7) << 4)));
            }
            int k0w = kc * 16 + ks * 8 + (lane >> 4) * 2;
            bf16x8 bfr[3];
#pragma unroll
            for (int fn = 0; fn < 3; ++fn) {
                uint32_t w0 = xs[slotc[fn] * 129 + k0w];
                uint32_t w1 = xs[slotc[fn] * 129 + k0w + 1];
                uint32_t c = (uint32_t)ccol[fn];
                union { uint32_t u[4]; bf16x8 v; } pk;
#pragma unroll
                for (int pq = 0; pq < 4; ++pq) {
                    uint32_t w = (pq < 2) ? w0 : w1;
                    uint32_t sh = (pq & 1) * 16;
                    uint32_t b0 = (w >> sh) & 0xffu, b1 = (w >> (sh + 8)) & 0xffu;
                    pk.u[pq] = ((b0 == c) ? 0x3F80u : 0u) | ((b1 == c) ? 0x3F800000u : 0u);
                }
                bfr[fn] = pk.v;
            }
#pragma unroll
            for (int fm = 0; fm < 4; ++fm)
#pragma unroll
                for (int fn = 0; fn < 3; ++fn)
                    acc[fm][fn] = __builtin_amdgcn_mfma_f32_16x16x32_bf16(
                        af[fm], bfr[fn], acc[fm][fn], 0, 0, 0);
        }
        __syncthreads();   // drains stage(kc+1) gl16s; orders dbuf reuse
    }

    // ---- epilogue: four 32-row windows through Racc (stride 193, 24.7KB)
    float vsum = 0.f;
    int srow = lane & 31;
    int s = wv * 2 + (lane >> 5);            // batch slot 0..15
#pragma unroll
    for (int w = 0; w < 4; ++w) {
        if (wm == (w >> 1)) {
#pragma unroll
            for (int f = 0; f < 2; ++f) {
                int fm = (w & 1) * 2 + f;
#pragma unroll
                for (int fn = 0; fn < 3; ++fn) {
                    int col = wn * 48 + fn * 16 + (lane & 15);
                    int rb = f * 16 + (lane >> 4) * 4;
#pragma unroll
                    for (int r = 0; r < 4; ++r)
                        Racc[(rb + r) * 193 + col] = acc[fm][fn][r];
                }
            }
        }
        __syncthreads();
        int ig = it * 128 + w * 32 + srow;
        float rz = 1.0f / Zg[(size_t)h * NL + ig];
        if (s < bcnt) {
            int b = bstart + s;
            uint32_t xw = xs[s * 129 + (ig >> 2)];
            int a = (int)((xw >> ((ig & 3) * 8)) & 0xffu);
            int off = b * 21 - n0;
            int clo = off < 0 ? -off : 0;
            int chi = (192 - off) < 21 ? (192 - off) : 21;
            float dot = 0.f;
            for (int c = clo; c < chi; ++c)
                dot += Vs[a * NAA + c] * Racc[srow * 193 + off + c];
            vsum += dot * rz;
        }
        __syncthreads();
    }
    // reduce the 32 rows within each half-wave, one atomic per (wave, half)
#pragma unroll
    for (int o = 1; o < 32; o <<= 1) vsum += __shfl_xor(vsum, o);
    if (srow == 0 && s < bcnt) atomicAdd(&out[bstart + s], -vsum);
}

// ---------------------------------------------------------------------------
extern "C" void kernel_launch(void* const* d_in, const int* in_sizes, int n_in,
                              void* d_out, int out_size, void* d_ws, size_t ws_size,
                              hipStream_t stream) {
    const int*   x = (const int*)d_in[0];
    const float* Q = (const float*)d_in[1];
    const float* K = (const float*)d_in[2];
    const float* V = (const float*)d_in[3];
    float* out = (float*)d_out;
    uint8_t* ws = (uint8_t*)d_ws;

    uint8_t*  Ewsw = ws + EW_OFF;
    uint32_t* Qb   = (uint32_t*)(ws + QB_OFF);
    uint32_t* Kb   = (uint32_t*)(ws + KB_OFF);
    float*    Zg   = (float*)(ws + ZG_OFF);

    hipMemsetAsync(d_out, 0, NB * sizeof(float), stream);
    prep_qk<<<8192, 256, 0, stream>>>(Q, K, Qb, Kb);
    (void)hipFuncSetAttribute((const void*)scores_mfma,
                              hipFuncAttributeMaxDynamicSharedMemorySize, SC_TOT);
    scores_mfma<<<256, 512, SC_TOT, stream>>>((const uint8_t*)Qb, (const uint8_t*)Kb,
                                              Ewsw, Zg);
    (void)hipFuncSetAttribute((const void*)gemm_energy,
                              hipFuncAttributeMaxDynamicSharedMemorySize, GE_TOT);
    gemm_energy<<<896, 512, GE_TOT, stream>>>((const uint8_t*)Ewsw, x, Zg, V, out);
}